// Round 11
// baseline (225.476 us; speedup 1.0000x reference)
//
#include <hip/hip_runtime.h>

#define NB 2
#define NN 50000
#define ND 128
#define NE 500000
#define NM (NB * NN)   // 100000 rows
#define LN_EPS 1e-5f

typedef __attribute__((ext_vector_type(8))) short short8;
typedef __attribute__((ext_vector_type(4))) float f32x4;
typedef __attribute__((ext_vector_type(4))) unsigned short us4;

// ---------------- workspace layout (bytes) ---- (r7/r8/r10-proven envelope) ----
// hb16  : bf16[NM][128]  @ 0            (25,600,000)  -- gather source; REUSED as yagg
// agg16 : bf16[NM][128]  @ 25,600,000   (25,600,000)
// deg   : int[NN]        @ 51,200,000
// start : int[NN+1]      @ 51,400,000
// cursor: int[NN]        @ 51,600,192
// elist : int[NE]        @ 51,800,192
// part  : int[128]       @ 53,800,192
// wmsg16: bf16[128][128] @ 53,801,216   (32,768)
#define HB_OFF     0
#define AGG_OFF    25600000
#define DEG_OFF    51200000
#define START_OFF  51400000
#define CURSOR_OFF 51600192
#define ELIST_OFF  51800192
#define PART_OFF   53800192
#define WMSG_OFF   53801216

#define SCAN_BLK 512
#define SCAN_NB ((NN + SCAN_BLK - 1) / SCAN_BLK)   // 98

// prep_kernel grid segmentation (r8-proven)
#define CONVH_NB ((NM * 16 + 255) / 256)   // 6250
#define CONVW_NB 8                         // 128*16 / 256
#define COUNT_NB ((NE + 255) / 256)        // 1954

__device__ __forceinline__ unsigned short f32_to_bf16(float f) {
    unsigned u = __builtin_bit_cast(unsigned, f);
    unsigned r = u + 0x7FFFu + ((u >> 16) & 1u);   // RNE
    return (unsigned short)(r >> 16);
}

__device__ __forceinline__ float bf16_to_f32(unsigned short s) {
    unsigned u = ((unsigned)s) << 16;
    return __builtin_bit_cast(float, u);
}

// ---------------- prep: convert_h + convert_wmsg + degree count (r8-proven) ----------------
__global__ void prep_kernel(const float* __restrict__ h, unsigned short* __restrict__ hb16,
                            const float* __restrict__ Wmsg, unsigned short* __restrict__ wmsg16,
                            const int* __restrict__ ei, int* __restrict__ deg) {
    const int bid = blockIdx.x;
    if (bid < CONVH_NB) {
        int i = bid * 256 + threadIdx.x;
        if (i >= NM * 16) return;
        int row = i >> 4;
        int c = i & 15;
        const float4 v0 = *(const float4*)(h + (size_t)row * ND + c * 8);
        const float4 v1 = *(const float4*)(h + (size_t)row * ND + c * 8 + 4);
        short8 o;
        o[0] = (short)f32_to_bf16(v0.x); o[1] = (short)f32_to_bf16(v0.y);
        o[2] = (short)f32_to_bf16(v0.z); o[3] = (short)f32_to_bf16(v0.w);
        o[4] = (short)f32_to_bf16(v1.x); o[5] = (short)f32_to_bf16(v1.y);
        o[6] = (short)f32_to_bf16(v1.z); o[7] = (short)f32_to_bf16(v1.w);
        *(short8*)(hb16 + (size_t)row * ND + c * 8) = o;
    } else if (bid < CONVH_NB + CONVW_NB) {
        int i = (bid - CONVH_NB) * 256 + threadIdx.x;   // 0 .. 2047
        int row = i >> 4;
        int c = i & 15;
        const float* src = Wmsg + (size_t)row * ND + c * 8;
        short8 o;
#pragma unroll
        for (int j = 0; j < 8; ++j) o[j] = (short)f32_to_bf16(src[j]);
        *(short8*)(wmsg16 + (size_t)row * ND + c * 8) = o;
    } else {
        int e = (bid - CONVH_NB - CONVW_NB) * 256 + threadIdx.x;
        if (e < NE) atomicAdd(&deg[ei[NE + e]], 1);
    }
}

// ---------------- CSR scan (proven) ----------------
__global__ void block_reduce_kernel(const int* __restrict__ deg, int* __restrict__ partials) {
    int i = blockIdx.x * SCAN_BLK + threadIdx.x;
    int v = (i < NN) ? deg[i] : 0;
#pragma unroll
    for (int off = 32; off > 0; off >>= 1) v += __shfl_down(v, off);
    __shared__ int wsum[SCAN_BLK / 64];
    int lane = threadIdx.x & 63;
    int w = threadIdx.x >> 6;
    if (lane == 0) wsum[w] = v;
    __syncthreads();
    if (threadIdx.x == 0) {
        int s = 0;
#pragma unroll
        for (int k = 0; k < SCAN_BLK / 64; ++k) s += wsum[k];
        partials[blockIdx.x] = s;
    }
}

__global__ void partial_scan_kernel(int* __restrict__ partials) {
    __shared__ int tmp[128];
    int t = threadIdx.x;
    int v = (t < SCAN_NB) ? partials[t] : 0;
    tmp[t] = v;
    __syncthreads();
    for (int off = 1; off < 128; off <<= 1) {
        int u = (t >= off) ? tmp[t - off] : 0;
        __syncthreads();
        tmp[t] += u;
        __syncthreads();
    }
    if (t < SCAN_NB) partials[t] = tmp[t] - v;
}

__global__ void block_scan_kernel(const int* __restrict__ deg, const int* __restrict__ partials,
                                  int* __restrict__ start, int* __restrict__ cursor) {
    __shared__ int tmp[SCAN_BLK];
    int t = threadIdx.x;
    int i = blockIdx.x * SCAN_BLK + t;
    int v = (i < NN) ? deg[i] : 0;
    tmp[t] = v;
    __syncthreads();
    for (int off = 1; off < SCAN_BLK; off <<= 1) {
        int u = (t >= off) ? tmp[t - off] : 0;
        __syncthreads();
        tmp[t] += u;
        __syncthreads();
    }
    if (i < NN) {
        int excl = tmp[t] - v + partials[blockIdx.x];
        start[i] = excl;
        cursor[i] = excl;
    }
    if (i == 0) start[NN] = NE;
}

__global__ void fill_kernel(const int* __restrict__ ei, int* __restrict__ cursor,
                            int* __restrict__ elist) {
    int e = blockIdx.x * blockDim.x + threadIdx.x;
    if (e < NE) {
        int d = ei[NE + e];
        int p = atomicAdd(&cursor[d], 1);
        elist[p] = ei[e];
    }
}

// ---------------- aggregation: bf16 gather, 8 edges in flight (r8-proven) ----------------
__global__ void agg_kernel(const unsigned short* __restrict__ hb16, const int* __restrict__ start,
                           const int* __restrict__ elist, unsigned short* __restrict__ agg) {
    int wid = (blockIdx.x * blockDim.x + threadIdx.x) >> 6;
    int l = threadIdx.x & 63;
    if (wid >= NM) return;
    int b = wid / NN;
    int n = wid - b * NN;
    int s0 = start[n];
    int d = start[n + 1] - s0;
    const int g = l >> 4;     // edge slot 0..3
    const int li = l & 15;    // 8-col chunk
    const unsigned short* hb = hb16 + (size_t)b * NN * ND;
    float s[8] = {0.f, 0.f, 0.f, 0.f, 0.f, 0.f, 0.f, 0.f};
    for (int j0 = 0; j0 < d; j0 += 64) {
        int mye = (j0 + l < d) ? elist[s0 + j0 + l] : -1;
        int cnt = (d - j0 < 64) ? (d - j0) : 64;
        int p = 0;
        for (; p + 8 <= cnt; p += 8) {
            int e0 = __shfl(mye, p + g);
            int e1 = __shfl(mye, p + 4 + g);
            const short8 v0 = *(const short8*)(hb + (size_t)e0 * ND + li * 8);
            const short8 v1 = *(const short8*)(hb + (size_t)e1 * ND + li * 8);
#pragma unroll
            for (int j = 0; j < 8; ++j) s[j] += bf16_to_f32((unsigned short)v0[j]);
#pragma unroll
            for (int j = 0; j < 8; ++j) s[j] += bf16_to_f32((unsigned short)v1[j]);
        }
        for (; p < cnt; p += 4) {
            int e = __shfl(mye, p + g);
            if (p + g < cnt) {
                const short8 v = *(const short8*)(hb + (size_t)e * ND + li * 8);
#pragma unroll
                for (int j = 0; j < 8; ++j) s[j] += bf16_to_f32((unsigned short)v[j]);
            }
        }
    }
#pragma unroll
    for (int j = 0; j < 8; ++j) {
        s[j] += __shfl_xor(s[j], 16);
        s[j] += __shfl_xor(s[j], 32);
    }
    if (g == 0) {
        float sc = 1.0f / (float)(d > 1 ? d : 1);
        short8 o;
#pragma unroll
        for (int j = 0; j < 8; ++j) o[j] = (short)f32_to_bf16(s[j] * sc);
        *(short8*)(agg + (size_t)wid * ND + li * 8) = o;
    }
}

// ---------------- agg-path MFMA: yagg = agg16 @ wmsg16^T (r7/r10-proven verbatim) ----------------
#define GBM 128

__global__ void mfma_agg_kernel(const unsigned short* __restrict__ agg16,
                                const unsigned short* __restrict__ wmsg16,
                                unsigned short* __restrict__ yagg) {
    const int t = threadIdx.x;
    const int w = t >> 6;
    const int l = t & 63;
    const int l15 = l & 15;
    const int lk = l >> 4;   // 0..3
    const int row0 = blockIdx.x * GBM + w * 32;

    f32x4 acc[2][8];
#pragma unroll
    for (int i = 0; i < 2; ++i)
#pragma unroll
        for (int j = 0; j < 8; ++j) acc[i][j] = (f32x4){0.f, 0.f, 0.f, 0.f};

    int rA0 = row0 + l15;      if (rA0 >= NM) rA0 = NM - 1;
    int rA1 = row0 + 16 + l15; if (rA1 >= NM) rA1 = NM - 1;
    const unsigned short* pa0 = agg16 + (size_t)rA0 * ND + lk * 8;
    const unsigned short* pa1 = agg16 + (size_t)rA1 * ND + lk * 8;
    const unsigned short* pb = wmsg16 + (size_t)l15 * ND + lk * 8;

#pragma unroll
    for (int ks = 0; ks < 4; ++ks) {
        const int k0 = ks * 32;
        const short8 a0 = *(const short8*)(pa0 + k0);
        const short8 a1 = *(const short8*)(pa1 + k0);
#pragma unroll
        for (int ct = 0; ct < 8; ++ct) {
            const short8 b = *(const short8*)(pb + ct * 16 * ND + k0);
            acc[0][ct] = __builtin_amdgcn_mfma_f32_16x16x32_bf16(a0, b, acc[0][ct], 0, 0, 0);
            acc[1][ct] = __builtin_amdgcn_mfma_f32_16x16x32_bf16(a1, b, acc[1][ct], 0, 0, 0);
        }
    }

    // C layout (proven): row = row0 + rt*16 + lk*4 + rg, col = ct*16 + l15
#pragma unroll
    for (int rt = 0; rt < 2; ++rt) {
#pragma unroll
        for (int rg = 0; rg < 4; ++rg) {
            const int row = row0 + rt * 16 + lk * 4 + rg;
            if (row < NM) {
                unsigned short* yrow = yagg + (size_t)row * ND;
#pragma unroll
                for (int ct = 0; ct < 8; ++ct)
                    yrow[ct * 16 + l15] = f32_to_bf16(acc[rt][ct][rg]);
            }
        }
    }
}

// ---------------- f32 self-GEMM + fused epilogue (r10 kernel + register-pipelined staging) ----------------
// Identical math/addressing to r10; the only change: slab kc+1's global loads are
// issued right after slab kc's LDS writes, hiding HBM/L2 latency under the FMA phase.
#define BM 128
#define BK 16
#define LROW 132   // 128 + 4 pad

__global__ void fused_gemm_kernel(const float* __restrict__ h, const unsigned short* __restrict__ yagg,
                                  const float* __restrict__ Wself, const float* __restrict__ bias,
                                  const float* __restrict__ gamma, const float* __restrict__ beta,
                                  float* __restrict__ out) {
    __shared__ float As[BK][LROW];
    __shared__ float Bs[BK][LROW];

    const int t = threadIdx.x;
    const int tx = t & 15;
    const int ty = t >> 4;
    const int tx4 = tx * 4;
    const int ty4 = ty * 4;
    const int row0 = blockIdx.x * BM;

    // staging addresses (r10 map, s-loop unrolled: f=t -> row ar; f=t+256 -> row ar+64; same kk4)
    const int kk4 = (t & 3) * 4;
    const int ar = t >> 2;               // 0..63
    int rgA0 = row0 + ar;       if (rgA0 >= NM) rgA0 = NM - 1;
    int rgA1 = row0 + ar + 64;  if (rgA1 >= NM) rgA1 = NM - 1;
    const float* pA0 = h + (size_t)rgA0 * ND + kk4;
    const float* pA1 = h + (size_t)rgA1 * ND + kk4;
    const float* pB0 = Wself + (size_t)ar * ND + kk4;
    const float* pB1 = Wself + (size_t)(ar + 64) * ND + kk4;

    float acc[8][8];
#pragma unroll
    for (int i = 0; i < 8; ++i)
#pragma unroll
        for (int j = 0; j < 8; ++j) acc[i][j] = 0.f;

    // prologue: issue slab 0 loads
    float4 ra0 = *(const float4*)(pA0);
    float4 ra1 = *(const float4*)(pA1);
    float4 rb0 = *(const float4*)(pB0);
    float4 rb1 = *(const float4*)(pB1);

    for (int kc = 0; kc < 8; ++kc) {
        __syncthreads();   // previous compute done; LDS free
        As[kk4 + 0][ar] = ra0.x; As[kk4 + 1][ar] = ra0.y;
        As[kk4 + 2][ar] = ra0.z; As[kk4 + 3][ar] = ra0.w;
        As[kk4 + 0][ar + 64] = ra1.x; As[kk4 + 1][ar + 64] = ra1.y;
        As[kk4 + 2][ar + 64] = ra1.z; As[kk4 + 3][ar + 64] = ra1.w;
        Bs[kk4 + 0][ar] = rb0.x; Bs[kk4 + 1][ar] = rb0.y;
        Bs[kk4 + 2][ar] = rb0.z; Bs[kk4 + 3][ar] = rb0.w;
        Bs[kk4 + 0][ar + 64] = rb1.x; Bs[kk4 + 1][ar + 64] = rb1.y;
        Bs[kk4 + 2][ar + 64] = rb1.z; Bs[kk4 + 3][ar + 64] = rb1.w;
        if (kc < 7) {
            const int k0n = (kc + 1) * BK;
            ra0 = *(const float4*)(pA0 + k0n);   // loads for next slab issue now,
            ra1 = *(const float4*)(pA1 + k0n);   // latency hides under this slab's FMAs
            rb0 = *(const float4*)(pB0 + k0n);
            rb1 = *(const float4*)(pB1 + k0n);
        }
        __syncthreads();   // staging visible
#pragma unroll
        for (int kk = 0; kk < BK; ++kk) {
            const float4 a0 = *(const float4*)(&As[kk][ty4]);
            const float4 a1 = *(const float4*)(&As[kk][ty4 + 64]);
            const float4 b0 = *(const float4*)(&Bs[kk][tx4]);
            const float4 b1 = *(const float4*)(&Bs[kk][tx4 + 64]);
            const float a[8] = {a0.x, a0.y, a0.z, a0.w, a1.x, a1.y, a1.z, a1.w};
            const float b[8] = {b0.x, b0.y, b0.z, b0.w, b1.x, b1.y, b1.z, b1.w};
#pragma unroll
            for (int i = 0; i < 8; ++i)
#pragma unroll
                for (int j = 0; j < 8; ++j)
                    acc[i][j] = fmaf(a[i], b[j], acc[i][j]);
        }
    }

    const float4 bi0 = *(const float4*)(bias + tx4);
    const float4 bi1 = *(const float4*)(bias + tx4 + 64);
    const float4 g0 = *(const float4*)(gamma + tx4);
    const float4 g1 = *(const float4*)(gamma + tx4 + 64);
    const float4 be0 = *(const float4*)(beta + tx4);
    const float4 be1 = *(const float4*)(beta + tx4 + 64);
    const float bb[8] = {bi0.x, bi0.y, bi0.z, bi0.w, bi1.x, bi1.y, bi1.z, bi1.w};
    const float gg[8] = {g0.x, g0.y, g0.z, g0.w, g1.x, g1.y, g1.z, g1.w};
    const float ee[8] = {be0.x, be0.y, be0.z, be0.w, be1.x, be1.y, be1.z, be1.w};
    const float inv = 1.0f / (float)ND;

#pragma unroll
    for (int i = 0; i < 8; ++i) {
        const int lm = (i < 4) ? (ty4 + i) : (64 + ty4 + i - 4);
        const int rg = row0 + lm;
        const bool valid = rg < NM;
        const int rc = valid ? rg : NM - 1;
        const float4 h0 = *(const float4*)(h + (size_t)rc * ND + tx4);
        const float4 h1 = *(const float4*)(h + (size_t)rc * ND + tx4 + 64);
        const us4 y0 = *(const us4*)(yagg + (size_t)rc * ND + tx4);
        const us4 y1 = *(const us4*)(yagg + (size_t)rc * ND + tx4 + 64);
        const float hh[8] = {h0.x, h0.y, h0.z, h0.w, h1.x, h1.y, h1.z, h1.w};
        const float yy[8] = {bf16_to_f32(y0[0]), bf16_to_f32(y0[1]), bf16_to_f32(y0[2]), bf16_to_f32(y0[3]),
                             bf16_to_f32(y1[0]), bf16_to_f32(y1[1]), bf16_to_f32(y1[2]), bf16_to_f32(y1[3])};
        float x[8];
        float sum = 0.f, sumsq = 0.f;
#pragma unroll
        for (int j = 0; j < 8; ++j) {
            float y = acc[i][j] + yy[j] + bb[j];
            float xv = hh[j] + (y > 0.f ? y : 0.f);
            x[j] = xv;
            sum += xv;
            sumsq = fmaf(xv, xv, sumsq);
        }
#pragma unroll
        for (int mask = 1; mask < 16; mask <<= 1) {
            sum += __shfl_xor(sum, mask);
            sumsq += __shfl_xor(sumsq, mask);
        }
        const float mu = sum * inv;
        const float var = sumsq * inv - mu * mu;
        const float rstd = rsqrtf(var + LN_EPS);
        if (valid) {
            float4 o0, o1;
            o0.x = (x[0] - mu) * rstd * gg[0] + ee[0];
            o0.y = (x[1] - mu) * rstd * gg[1] + ee[1];
            o0.z = (x[2] - mu) * rstd * gg[2] + ee[2];
            o0.w = (x[3] - mu) * rstd * gg[3] + ee[3];
            o1.x = (x[4] - mu) * rstd * gg[4] + ee[4];
            o1.y = (x[5] - mu) * rstd * gg[5] + ee[5];
            o1.z = (x[6] - mu) * rstd * gg[6] + ee[6];
            o1.w = (x[7] - mu) * rstd * gg[7] + ee[7];
            *(float4*)(out + (size_t)rg * ND + tx4) = o0;
            *(float4*)(out + (size_t)rg * ND + tx4 + 64) = o1;
        }
    }
}

extern "C" void kernel_launch(void* const* d_in, const int* in_sizes, int n_in,
                              void* d_out, int out_size, void* d_ws, size_t ws_size,
                              hipStream_t stream) {
    const float* h = (const float*)d_in[0];
    const int* ei = (const int*)d_in[1];
    const float* Wself = (const float*)d_in[2];
    const float* Wmsg = (const float*)d_in[3];
    const float* bias = (const float*)d_in[4];
    const float* gamma = (const float*)d_in[5];
    const float* beta = (const float*)d_in[6];
    float* out = (float*)d_out;

    char* ws = (char*)d_ws;
    unsigned short* hb16 = (unsigned short*)(ws + HB_OFF);
    unsigned short* yagg = (unsigned short*)(ws + HB_OFF);   // reuses hb16 after agg
    unsigned short* agg16 = (unsigned short*)(ws + AGG_OFF);
    unsigned short* wmsg16 = (unsigned short*)(ws + WMSG_OFF);
    int* deg = (int*)(ws + DEG_OFF);
    int* start = (int*)(ws + START_OFF);
    int* cursor = (int*)(ws + CURSOR_OFF);
    int* elist = (int*)(ws + ELIST_OFF);
    int* partials = (int*)(ws + PART_OFF);

    hipMemsetAsync(deg, 0, NN * sizeof(int), stream);

    prep_kernel<<<CONVH_NB + CONVW_NB + COUNT_NB, 256, 0, stream>>>(h, hb16, Wmsg, wmsg16, ei, deg);
    block_reduce_kernel<<<SCAN_NB, SCAN_BLK, 0, stream>>>(deg, partials);
    partial_scan_kernel<<<1, 128, 0, stream>>>(partials);
    block_scan_kernel<<<SCAN_NB, SCAN_BLK, 0, stream>>>(deg, partials, start, cursor);
    fill_kernel<<<(NE + 255) / 256, 256, 0, stream>>>(ei, cursor, elist);

    agg_kernel<<<(NM * 64 + 255) / 256, 256, 0, stream>>>(hb16, start, elist, agg16);

    int nblocks = (NM + GBM - 1) / GBM;  // 782
    mfma_agg_kernel<<<nblocks, 256, 0, stream>>>(agg16, wmsg16, yagg);   // yagg overwrites hb16

    fused_gemm_kernel<<<nblocks, 256, 0, stream>>>(h, yagg, Wself, bias, gamma, beta, out);
}

// Round 12
// 199.359 us; speedup vs baseline: 1.1310x; 1.1310x over previous
//
#include <hip/hip_runtime.h>

#define NB 2
#define NN 50000
#define ND 128
#define NE 500000
#define NM (NB * NN)   // 100000 rows
#define LN_EPS 1e-5f

typedef __attribute__((ext_vector_type(8))) short short8;
typedef __attribute__((ext_vector_type(4))) float f32x4;
typedef __attribute__((ext_vector_type(4))) unsigned short us4;

// ---------------- workspace layout (bytes) ---- (r7/r8/r10-proven envelope) ----
// hb16  : bf16[NM][128]  @ 0            (25,600,000)  -- gather source; REUSED as yagg
// agg16 : bf16[NM][128]  @ 25,600,000   (25,600,000)
// deg   : int[NN]        @ 51,200,000
// start : int[NN+1]      @ 51,400,000
// cursor: int[NN]        @ 51,600,192
// elist : int[NE]        @ 51,800,192
// part  : int[128]       @ 53,800,192
// wmsg16: bf16[128][128] @ 53,801,216   (32,768)
#define HB_OFF     0
#define AGG_OFF    25600000
#define DEG_OFF    51200000
#define START_OFF  51400000
#define CURSOR_OFF 51600192
#define ELIST_OFF  51800192
#define PART_OFF   53800192
#define WMSG_OFF   53801216

#define SCAN_BLK 512
#define SCAN_NB ((NN + SCAN_BLK - 1) / SCAN_BLK)   // 98

// prep_kernel grid segmentation (r8-proven)
#define CONVH_NB ((NM * 16 + 255) / 256)   // 6250
#define CONVW_NB 8                         // 128*16 / 256
#define COUNT_NB ((NE + 255) / 256)        // 1954

__device__ __forceinline__ unsigned short f32_to_bf16(float f) {
    unsigned u = __builtin_bit_cast(unsigned, f);
    unsigned r = u + 0x7FFFu + ((u >> 16) & 1u);   // RNE
    return (unsigned short)(r >> 16);
}

__device__ __forceinline__ float bf16_to_f32(unsigned short s) {
    unsigned u = ((unsigned)s) << 16;
    return __builtin_bit_cast(float, u);
}

// ---------------- prep: convert_h + convert_wmsg + degree count (r8-proven) ----------------
__global__ void prep_kernel(const float* __restrict__ h, unsigned short* __restrict__ hb16,
                            const float* __restrict__ Wmsg, unsigned short* __restrict__ wmsg16,
                            const int* __restrict__ ei, int* __restrict__ deg) {
    const int bid = blockIdx.x;
    if (bid < CONVH_NB) {
        int i = bid * 256 + threadIdx.x;
        if (i >= NM * 16) return;
        int row = i >> 4;
        int c = i & 15;
        const float4 v0 = *(const float4*)(h + (size_t)row * ND + c * 8);
        const float4 v1 = *(const float4*)(h + (size_t)row * ND + c * 8 + 4);
        short8 o;
        o[0] = (short)f32_to_bf16(v0.x); o[1] = (short)f32_to_bf16(v0.y);
        o[2] = (short)f32_to_bf16(v0.z); o[3] = (short)f32_to_bf16(v0.w);
        o[4] = (short)f32_to_bf16(v1.x); o[5] = (short)f32_to_bf16(v1.y);
        o[6] = (short)f32_to_bf16(v1.z); o[7] = (short)f32_to_bf16(v1.w);
        *(short8*)(hb16 + (size_t)row * ND + c * 8) = o;
    } else if (bid < CONVH_NB + CONVW_NB) {
        int i = (bid - CONVH_NB) * 256 + threadIdx.x;   // 0 .. 2047
        int row = i >> 4;
        int c = i & 15;
        const float* src = Wmsg + (size_t)row * ND + c * 8;
        short8 o;
#pragma unroll
        for (int j = 0; j < 8; ++j) o[j] = (short)f32_to_bf16(src[j]);
        *(short8*)(wmsg16 + (size_t)row * ND + c * 8) = o;
    } else {
        int e = (bid - CONVH_NB - CONVW_NB) * 256 + threadIdx.x;
        if (e < NE) atomicAdd(&deg[ei[NE + e]], 1);
    }
}

// ---------------- CSR scan (proven) ----------------
__global__ void block_reduce_kernel(const int* __restrict__ deg, int* __restrict__ partials) {
    int i = blockIdx.x * SCAN_BLK + threadIdx.x;
    int v = (i < NN) ? deg[i] : 0;
#pragma unroll
    for (int off = 32; off > 0; off >>= 1) v += __shfl_down(v, off);
    __shared__ int wsum[SCAN_BLK / 64];
    int lane = threadIdx.x & 63;
    int w = threadIdx.x >> 6;
    if (lane == 0) wsum[w] = v;
    __syncthreads();
    if (threadIdx.x == 0) {
        int s = 0;
#pragma unroll
        for (int k = 0; k < SCAN_BLK / 64; ++k) s += wsum[k];
        partials[blockIdx.x] = s;
    }
}

__global__ void partial_scan_kernel(int* __restrict__ partials) {
    __shared__ int tmp[128];
    int t = threadIdx.x;
    int v = (t < SCAN_NB) ? partials[t] : 0;
    tmp[t] = v;
    __syncthreads();
    for (int off = 1; off < 128; off <<= 1) {
        int u = (t >= off) ? tmp[t - off] : 0;
        __syncthreads();
        tmp[t] += u;
        __syncthreads();
    }
    if (t < SCAN_NB) partials[t] = tmp[t] - v;
}

__global__ void block_scan_kernel(const int* __restrict__ deg, const int* __restrict__ partials,
                                  int* __restrict__ start, int* __restrict__ cursor) {
    __shared__ int tmp[SCAN_BLK];
    int t = threadIdx.x;
    int i = blockIdx.x * SCAN_BLK + t;
    int v = (i < NN) ? deg[i] : 0;
    tmp[t] = v;
    __syncthreads();
    for (int off = 1; off < SCAN_BLK; off <<= 1) {
        int u = (t >= off) ? tmp[t - off] : 0;
        __syncthreads();
        tmp[t] += u;
        __syncthreads();
    }
    if (i < NN) {
        int excl = tmp[t] - v + partials[blockIdx.x];
        start[i] = excl;
        cursor[i] = excl;
    }
    if (i == 0) start[NN] = NE;
}

__global__ void fill_kernel(const int* __restrict__ ei, int* __restrict__ cursor,
                            int* __restrict__ elist) {
    int e = blockIdx.x * blockDim.x + threadIdx.x;
    if (e < NE) {
        int d = ei[NE + e];
        int p = atomicAdd(&cursor[d], 1);
        elist[p] = ei[e];
    }
}

// ---------------- aggregation: bf16 gather, 8 edges in flight (r8-proven) ----------------
__global__ void agg_kernel(const unsigned short* __restrict__ hb16, const int* __restrict__ start,
                           const int* __restrict__ elist, unsigned short* __restrict__ agg) {
    int wid = (blockIdx.x * blockDim.x + threadIdx.x) >> 6;
    int l = threadIdx.x & 63;
    if (wid >= NM) return;
    int b = wid / NN;
    int n = wid - b * NN;
    int s0 = start[n];
    int d = start[n + 1] - s0;
    const int g = l >> 4;     // edge slot 0..3
    const int li = l & 15;    // 8-col chunk
    const unsigned short* hb = hb16 + (size_t)b * NN * ND;
    float s[8] = {0.f, 0.f, 0.f, 0.f, 0.f, 0.f, 0.f, 0.f};
    for (int j0 = 0; j0 < d; j0 += 64) {
        int mye = (j0 + l < d) ? elist[s0 + j0 + l] : -1;
        int cnt = (d - j0 < 64) ? (d - j0) : 64;
        int p = 0;
        for (; p + 8 <= cnt; p += 8) {
            int e0 = __shfl(mye, p + g);
            int e1 = __shfl(mye, p + 4 + g);
            const short8 v0 = *(const short8*)(hb + (size_t)e0 * ND + li * 8);
            const short8 v1 = *(const short8*)(hb + (size_t)e1 * ND + li * 8);
#pragma unroll
            for (int j = 0; j < 8; ++j) s[j] += bf16_to_f32((unsigned short)v0[j]);
#pragma unroll
            for (int j = 0; j < 8; ++j) s[j] += bf16_to_f32((unsigned short)v1[j]);
        }
        for (; p < cnt; p += 4) {
            int e = __shfl(mye, p + g);
            if (p + g < cnt) {
                const short8 v = *(const short8*)(hb + (size_t)e * ND + li * 8);
#pragma unroll
                for (int j = 0; j < 8; ++j) s[j] += bf16_to_f32((unsigned short)v[j]);
            }
        }
    }
#pragma unroll
    for (int j = 0; j < 8; ++j) {
        s[j] += __shfl_xor(s[j], 16);
        s[j] += __shfl_xor(s[j], 32);
    }
    if (g == 0) {
        float sc = 1.0f / (float)(d > 1 ? d : 1);
        short8 o;
#pragma unroll
        for (int j = 0; j < 8; ++j) o[j] = (short)f32_to_bf16(s[j] * sc);
        *(short8*)(agg + (size_t)wid * ND + li * 8) = o;
    }
}

// ---------------- agg-path MFMA: yagg = agg16 @ wmsg16^T (r7/r10-proven verbatim) ----------------
#define GBM 128

__global__ void mfma_agg_kernel(const unsigned short* __restrict__ agg16,
                                const unsigned short* __restrict__ wmsg16,
                                unsigned short* __restrict__ yagg) {
    const int t = threadIdx.x;
    const int w = t >> 6;
    const int l = t & 63;
    const int l15 = l & 15;
    const int lk = l >> 4;   // 0..3
    const int row0 = blockIdx.x * GBM + w * 32;

    f32x4 acc[2][8];
#pragma unroll
    for (int i = 0; i < 2; ++i)
#pragma unroll
        for (int j = 0; j < 8; ++j) acc[i][j] = (f32x4){0.f, 0.f, 0.f, 0.f};

    int rA0 = row0 + l15;      if (rA0 >= NM) rA0 = NM - 1;
    int rA1 = row0 + 16 + l15; if (rA1 >= NM) rA1 = NM - 1;
    const unsigned short* pa0 = agg16 + (size_t)rA0 * ND + lk * 8;
    const unsigned short* pa1 = agg16 + (size_t)rA1 * ND + lk * 8;
    const unsigned short* pb = wmsg16 + (size_t)l15 * ND + lk * 8;

#pragma unroll
    for (int ks = 0; ks < 4; ++ks) {
        const int k0 = ks * 32;
        const short8 a0 = *(const short8*)(pa0 + k0);
        const short8 a1 = *(const short8*)(pa1 + k0);
#pragma unroll
        for (int ct = 0; ct < 8; ++ct) {
            const short8 b = *(const short8*)(pb + ct * 16 * ND + k0);
            acc[0][ct] = __builtin_amdgcn_mfma_f32_16x16x32_bf16(a0, b, acc[0][ct], 0, 0, 0);
            acc[1][ct] = __builtin_amdgcn_mfma_f32_16x16x32_bf16(a1, b, acc[1][ct], 0, 0, 0);
        }
    }

    // C layout (proven): row = row0 + rt*16 + lk*4 + rg, col = ct*16 + l15
#pragma unroll
    for (int rt = 0; rt < 2; ++rt) {
#pragma unroll
        for (int rg = 0; rg < 4; ++rg) {
            const int row = row0 + rt * 16 + lk * 4 + rg;
            if (row < NM) {
                unsigned short* yrow = yagg + (size_t)row * ND;
#pragma unroll
                for (int ct = 0; ct < 8; ++ct)
                    yrow[ct * 16 + l15] = f32_to_bf16(acc[rt][ct][rg]);
            }
        }
    }
}

// ---------------- f32 self-GEMM + fused epilogue (r11 pipelined + launch_bounds fix) ----------------
// r11 regression diagnosed as scratch spill of the staged registers (WRITE_SIZE +112MB at
// VGPR_Count 64). __launch_bounds__(256, 2) raises the VGPR cap so staging stays in registers.
#define BM 128
#define BK 16
#define LROW 132   // 128 + 4 pad

__global__ __launch_bounds__(256, 2)
void fused_gemm_kernel(const float* __restrict__ h, const unsigned short* __restrict__ yagg,
                       const float* __restrict__ Wself, const float* __restrict__ bias,
                       const float* __restrict__ gamma, const float* __restrict__ beta,
                       float* __restrict__ out) {
    __shared__ float As[BK][LROW];
    __shared__ float Bs[BK][LROW];

    const int t = threadIdx.x;
    const int tx = t & 15;
    const int ty = t >> 4;
    const int tx4 = tx * 4;
    const int ty4 = ty * 4;
    const int row0 = blockIdx.x * BM;

    // staging addresses (r10 map, s-loop unrolled: f=t -> row ar; f=t+256 -> row ar+64; same kk4)
    const int kk4 = (t & 3) * 4;
    const int ar = t >> 2;               // 0..63
    int rgA0 = row0 + ar;       if (rgA0 >= NM) rgA0 = NM - 1;
    int rgA1 = row0 + ar + 64;  if (rgA1 >= NM) rgA1 = NM - 1;
    const float* pA0 = h + (size_t)rgA0 * ND + kk4;
    const float* pA1 = h + (size_t)rgA1 * ND + kk4;
    const float* pB0 = Wself + (size_t)ar * ND + kk4;
    const float* pB1 = Wself + (size_t)(ar + 64) * ND + kk4;

    float acc[8][8];
#pragma unroll
    for (int i = 0; i < 8; ++i)
#pragma unroll
        for (int j = 0; j < 8; ++j) acc[i][j] = 0.f;

    // prologue: issue slab 0 loads
    float4 ra0 = *(const float4*)(pA0);
    float4 ra1 = *(const float4*)(pA1);
    float4 rb0 = *(const float4*)(pB0);
    float4 rb1 = *(const float4*)(pB1);

    for (int kc = 0; kc < 8; ++kc) {
        __syncthreads();   // previous compute done; LDS free
        As[kk4 + 0][ar] = ra0.x; As[kk4 + 1][ar] = ra0.y;
        As[kk4 + 2][ar] = ra0.z; As[kk4 + 3][ar] = ra0.w;
        As[kk4 + 0][ar + 64] = ra1.x; As[kk4 + 1][ar + 64] = ra1.y;
        As[kk4 + 2][ar + 64] = ra1.z; As[kk4 + 3][ar + 64] = ra1.w;
        Bs[kk4 + 0][ar] = rb0.x; Bs[kk4 + 1][ar] = rb0.y;
        Bs[kk4 + 2][ar] = rb0.z; Bs[kk4 + 3][ar] = rb0.w;
        Bs[kk4 + 0][ar + 64] = rb1.x; Bs[kk4 + 1][ar + 64] = rb1.y;
        Bs[kk4 + 2][ar + 64] = rb1.z; Bs[kk4 + 3][ar + 64] = rb1.w;
        if (kc < 7) {
            const int k0n = (kc + 1) * BK;
            ra0 = *(const float4*)(pA0 + k0n);   // loads for next slab issue now,
            ra1 = *(const float4*)(pA1 + k0n);   // latency hides under this slab's FMAs
            rb0 = *(const float4*)(pB0 + k0n);
            rb1 = *(const float4*)(pB1 + k0n);
        }
        __syncthreads();   // staging visible
#pragma unroll
        for (int kk = 0; kk < BK; ++kk) {
            const float4 a0 = *(const float4*)(&As[kk][ty4]);
            const float4 a1 = *(const float4*)(&As[kk][ty4 + 64]);
            const float4 b0 = *(const float4*)(&Bs[kk][tx4]);
            const float4 b1 = *(const float4*)(&Bs[kk][tx4 + 64]);
            const float a[8] = {a0.x, a0.y, a0.z, a0.w, a1.x, a1.y, a1.z, a1.w};
            const float b[8] = {b0.x, b0.y, b0.z, b0.w, b1.x, b1.y, b1.z, b1.w};
#pragma unroll
            for (int i = 0; i < 8; ++i)
#pragma unroll
                for (int j = 0; j < 8; ++j)
                    acc[i][j] = fmaf(a[i], b[j], acc[i][j]);
        }
    }

    const float4 bi0 = *(const float4*)(bias + tx4);
    const float4 bi1 = *(const float4*)(bias + tx4 + 64);
    const float4 g0 = *(const float4*)(gamma + tx4);
    const float4 g1 = *(const float4*)(gamma + tx4 + 64);
    const float4 be0 = *(const float4*)(beta + tx4);
    const float4 be1 = *(const float4*)(beta + tx4 + 64);
    const float bb[8] = {bi0.x, bi0.y, bi0.z, bi0.w, bi1.x, bi1.y, bi1.z, bi1.w};
    const float gg[8] = {g0.x, g0.y, g0.z, g0.w, g1.x, g1.y, g1.z, g1.w};
    const float ee[8] = {be0.x, be0.y, be0.z, be0.w, be1.x, be1.y, be1.z, be1.w};
    const float inv = 1.0f / (float)ND;

#pragma unroll
    for (int i = 0; i < 8; ++i) {
        const int lm = (i < 4) ? (ty4 + i) : (64 + ty4 + i - 4);
        const int rg = row0 + lm;
        const bool valid = rg < NM;
        const int rc = valid ? rg : NM - 1;
        const float4 h0 = *(const float4*)(h + (size_t)rc * ND + tx4);
        const float4 h1 = *(const float4*)(h + (size_t)rc * ND + tx4 + 64);
        const us4 y0 = *(const us4*)(yagg + (size_t)rc * ND + tx4);
        const us4 y1 = *(const us4*)(yagg + (size_t)rc * ND + tx4 + 64);
        const float hh[8] = {h0.x, h0.y, h0.z, h0.w, h1.x, h1.y, h1.z, h1.w};
        const float yy[8] = {bf16_to_f32(y0[0]), bf16_to_f32(y0[1]), bf16_to_f32(y0[2]), bf16_to_f32(y0[3]),
                             bf16_to_f32(y1[0]), bf16_to_f32(y1[1]), bf16_to_f32(y1[2]), bf16_to_f32(y1[3])};
        float x[8];
        float sum = 0.f, sumsq = 0.f;
#pragma unroll
        for (int j = 0; j < 8; ++j) {
            float y = acc[i][j] + yy[j] + bb[j];
            float xv = hh[j] + (y > 0.f ? y : 0.f);
            x[j] = xv;
            sum += xv;
            sumsq = fmaf(xv, xv, sumsq);
        }
#pragma unroll
        for (int mask = 1; mask < 16; mask <<= 1) {
            sum += __shfl_xor(sum, mask);
            sumsq += __shfl_xor(sumsq, mask);
        }
        const float mu = sum * inv;
        const float var = sumsq * inv - mu * mu;
        const float rstd = rsqrtf(var + LN_EPS);
        if (valid) {
            float4 o0, o1;
            o0.x = (x[0] - mu) * rstd * gg[0] + ee[0];
            o0.y = (x[1] - mu) * rstd * gg[1] + ee[1];
            o0.z = (x[2] - mu) * rstd * gg[2] + ee[2];
            o0.w = (x[3] - mu) * rstd * gg[3] + ee[3];
            o1.x = (x[4] - mu) * rstd * gg[4] + ee[4];
            o1.y = (x[5] - mu) * rstd * gg[5] + ee[5];
            o1.z = (x[6] - mu) * rstd * gg[6] + ee[6];
            o1.w = (x[7] - mu) * rstd * gg[7] + ee[7];
            *(float4*)(out + (size_t)rg * ND + tx4) = o0;
            *(float4*)(out + (size_t)rg * ND + tx4 + 64) = o1;
        }
    }
}

extern "C" void kernel_launch(void* const* d_in, const int* in_sizes, int n_in,
                              void* d_out, int out_size, void* d_ws, size_t ws_size,
                              hipStream_t stream) {
    const float* h = (const float*)d_in[0];
    const int* ei = (const int*)d_in[1];
    const float* Wself = (const float*)d_in[2];
    const float* Wmsg = (const float*)d_in[3];
    const float* bias = (const float*)d_in[4];
    const float* gamma = (const float*)d_in[5];
    const float* beta = (const float*)d_in[6];
    float* out = (float*)d_out;

    char* ws = (char*)d_ws;
    unsigned short* hb16 = (unsigned short*)(ws + HB_OFF);
    unsigned short* yagg = (unsigned short*)(ws + HB_OFF);   // reuses hb16 after agg
    unsigned short* agg16 = (unsigned short*)(ws + AGG_OFF);
    unsigned short* wmsg16 = (unsigned short*)(ws + WMSG_OFF);
    int* deg = (int*)(ws + DEG_OFF);
    int* start = (int*)(ws + START_OFF);
    int* cursor = (int*)(ws + CURSOR_OFF);
    int* elist = (int*)(ws + ELIST_OFF);
    int* partials = (int*)(ws + PART_OFF);

    hipMemsetAsync(deg, 0, NN * sizeof(int), stream);

    prep_kernel<<<CONVH_NB + CONVW_NB + COUNT_NB, 256, 0, stream>>>(h, hb16, Wmsg, wmsg16, ei, deg);
    block_reduce_kernel<<<SCAN_NB, SCAN_BLK, 0, stream>>>(deg, partials);
    partial_scan_kernel<<<1, 128, 0, stream>>>(partials);
    block_scan_kernel<<<SCAN_NB, SCAN_BLK, 0, stream>>>(deg, partials, start, cursor);
    fill_kernel<<<(NE + 255) / 256, 256, 0, stream>>>(ei, cursor, elist);

    agg_kernel<<<(NM * 64 + 255) / 256, 256, 0, stream>>>(hb16, start, elist, agg16);

    int nblocks = (NM + GBM - 1) / GBM;  // 782
    mfma_agg_kernel<<<nblocks, 256, 0, stream>>>(agg16, wmsg16, yagg);   // yagg overwrites hb16

    fused_gemm_kernel<<<nblocks, 256, 0, stream>>>(h, yagg, Wself, bias, gamma, beta, out);
}